// Round 9
// baseline (456.427 us; speedup 1.0000x reference)
//
#include <hip/hip_runtime.h>

#define SEQ   512
#define BATCH 4
#define NN    128
#define HID   64
#define G4    256   // 4*HID gates per layer
#define MAGIC 0x13579BDF

typedef _Float16 half2v __attribute__((ext_vector_type(2)));

// Fast activations: v_exp_f32 + v_rcp_f32 (abs err ~1e-6, threshold is 1e-3)
__device__ __forceinline__ float frcp(float x)  { return __builtin_amdgcn_rcpf(x); }
__device__ __forceinline__ float fsigm(float x) { return frcp(1.f + __expf(-x)); }
__device__ __forceinline__ float ftanh(float x) { return 1.f - 2.f * frcp(1.f + __expf(2.f * x)); }
__device__ __forceinline__ float lrelu(float x) { return x > 0.f ? x : 0.2f * x; }
__device__ __forceinline__ float dot4f(float4 w, float4 h) {
  return fmaf(w.x, h.x, fmaf(w.y, h.y, fmaf(w.z, h.z, w.w * h.w)));
}
__device__ __forceinline__ void pin4(float4& v) {
  asm volatile("" : "+v"(v.x), "+v"(v.y), "+v"(v.z), "+v"(v.w));
}
__device__ __forceinline__ half2v u2h(unsigned u) {
  return __builtin_bit_cast(half2v, u);
}
// v_dot2_f32_f16: 2 f16 MACs, f32 accumulate (exact products, f32 sum).
__device__ __forceinline__ float fdot2(half2v a, half2v b, float c) {
#if __has_builtin(__builtin_amdgcn_fdot2)
  return __builtin_amdgcn_fdot2(a, b, c, false);
#else
  float d = c;
  asm("v_dot2_f32_f16 %0, %1, %2, %0" : "+v"(d) : "v"(a), "v"(b));
  return d;
#endif
}
// 16-elem f16 dot: 8 chained v_dot2 (w = 8 half2, h = two uint4 of packed f16).
__device__ __forceinline__ float dot8h(const half2v* w, const uint4& a,
                                       const uint4& b, float acc) {
  acc = fdot2(w[0], u2h(a.x), acc);
  acc = fdot2(w[1], u2h(a.y), acc);
  acc = fdot2(w[2], u2h(a.z), acc);
  acc = fdot2(w[3], u2h(a.w), acc);
  acc = fdot2(w[4], u2h(b.x), acc);
  acc = fdot2(w[5], u2h(b.y), acc);
  acc = fdot2(w[6], u2h(b.z), acc);
  acc = fdot2(w[7], u2h(b.w), acc);
  return acc;
}

// LDS-only barrier: s_waitcnt lgkmcnt(0) + s_barrier, NO vmcnt(0) drain.
#define BAR_LDS() asm volatile("s_waitcnt lgkmcnt(0)\n\ts_barrier" ::: "memory")

// ---------------------------------------------------------------------------
// fused_all: ONE kernel, 132 blocks x 256 threads.
//   blocks 0-3   : LSTM scan + heads, gated on banded X0 flags.
//   blocks 4-131 : X0 producer, band-interleaved; blocks 4-7 then GAT.
// R20: epoch = 8 intervals (was 4) with 16-deep buffers -> 66 barriers
//   (was 130). X0 prefetch 8-deep with rolling in-place reloads (slot i
//   reloaded right after its consumption, ~7-interval lead). Schedule:
//     wave0 @K: h0[K]    = gates(Whh0*h0[K-1] + X0[K])     (intra-wave loop)
//     wave1 @K: SB[K-8]  = Wih1*h0[K-8] + b1               (>=1 epoch behind)
//     wave2 @K: h1[K-16] = gates(SB[K-16] + Whh1*h1[K-17]) (>=1 epoch behind)
//     wave3: frontier polls + barriers only.
//   528 intervals; h1[511] lands in hb1[511&15] = hb1[15].
// ---------------------------------------------------------------------------
__global__ __attribute__((amdgpu_flat_work_group_size(256, 256),
                          amdgpu_waves_per_eu(1, 4)))
void fused_all(
    const float* __restrict__ x, const int* __restrict__ adj,
    const float* __restrict__ emb_w, const float* __restrict__ emb_b,
    const float* __restrict__ W1, const float* __restrict__ a1,
    const float* __restrict__ W2, const float* __restrict__ a2,
    const float* __restrict__ Wih0, const float* __restrict__ Whh0,
    const float* __restrict__ bih0, const float* __restrict__ bhh0,
    const float* __restrict__ Wih1, const float* __restrict__ Whh1,
    const float* __restrict__ bih1, const float* __restrict__ bhh1,
    const float* __restrict__ dw1, const float* __restrict__ db1,
    const float* __restrict__ dw2, const float* __restrict__ db2,
    const float* __restrict__ rw1, const float* __restrict__ rb1,
    const float* __restrict__ rw2, const float* __restrict__ rb2,
    const float* __restrict__ vw1, const float* __restrict__ vb1,
    const float* __restrict__ vw2, const float* __restrict__ vb2,
    float* __restrict__ X0T, float* __restrict__ xg,
    int* __restrict__ flags, float* __restrict__ out)
{
  const int bid = blockIdx.x;
  const int tid = threadIdx.x;

  if (bid >= 4) {
    // =================== PRODUCER: band-interleaved X0 ===================
    const int c = bid - 4;
    __shared__ __align__(16) float xls[NN];
    {
      const int g = tid;                       // one gate per thread
      float4 w4[32];
      {
        const float4* wp = reinterpret_cast<const float4*>(Wih0 + g * NN);
#pragma unroll
        for (int i = 0; i < 32; ++i) w4[i] = wp[i];
#pragma unroll
        for (int i = 0; i < 32; ++i) pin4(w4[i]);
      }
      const float bsum = bih0[g] + bhh0[g];
      for (int phase = 0; phase < 4; ++phase) {
        const int T = c + 128 * phase;
        for (int bb = 0; bb < BATCH; ++bb) {
          if (tid < NN) xls[tid] = x[(bb * SEQ + T) * NN + tid];
          __syncthreads();
          {
            const float4* hp = reinterpret_cast<const float4*>(xls);
            float p0 = 0.f, p1 = 0.f, p2 = 0.f, p3 = 0.f;
#pragma unroll
            for (int k = 0; k < 32; k += 4) {
              p0 += dot4f(w4[k],     hp[k]);
              p1 += dot4f(w4[k + 1], hp[k + 1]);
              p2 += dot4f(w4[k + 2], hp[k + 2]);
              p3 += dot4f(w4[k + 3], hp[k + 3]);
            }
            X0T[(4 * T + bb) * G4 + (g & 63) * 4 + (g >> 6)] =
                ((p0 + p1) + (p2 + p3)) + bsum;
          }
          __syncthreads();   // drains this block's X0 stores before flag release
        }
        if (tid == 0 && phase == 0)
          __hip_atomic_store(&flags[c], MAGIC, __ATOMIC_RELEASE,
                             __HIP_MEMORY_SCOPE_AGENT);
        if (tid == 0 && phase == 3)
          __hip_atomic_store(&flags[128 + c], MAGIC, __ATOMIC_RELEASE,
                             __HIP_MEMORY_SCOPE_AGENT);
      }
    }
    if (bid >= 8) return;

    // =================== GAT (blocks 4-7, batch b) ===================
    const int b = bid - 4;
    __shared__ float adjm[NN * 129];
    __shared__ __align__(16) float gxls[NN];
    __shared__ float u[16], v[16];
    __shared__ float Wh2[NN][9];
    __shared__ float f1b[NN], f2b[NN];
    __shared__ float p[NN];

    for (int idx = tid; idx < NN * NN; idx += 256)
      adjm[(idx >> 7) * 129 + (idx & 127)] = (adj[idx] > 0) ? 1.f : 0.f;
    if (tid < NN) gxls[tid] = x[(b * SEQ + (SEQ - 1)) * NN + tid];
    if (tid < 16) {
      float uu = 0.f, vv = 0.f;
      for (int fp = 0; fp < 16; ++fp) {
        uu += emb_w[fp] * W1[fp * 16 + tid];
        vv += emb_b[fp] * W1[fp * 16 + tid];
      }
      u[tid] = uu; v[tid] = vv;
    }
    __syncthreads();
    float s1 = 0.f, t1 = 0.f, s2 = 0.f, t2 = 0.f;
    for (int f = 0; f < 16; ++f) {
      s1 += u[f] * a1[f];      t1 += v[f] * a1[f];
      s2 += u[f] * a1[16 + f]; t2 += v[f] * a1[16 + f];
    }
    if (tid < NN) {
      const int i = tid;
      const float f1i = gxls[i] * s1 + t1;
      float m = -1e30f;
      for (int j = 0; j < NN; ++j)
        if (adjm[i * 129 + j] != 0.f)
          m = fmaxf(m, lrelu(f1i + gxls[j] * s2 + t2));
      float ssum = 0.f, ps = 0.f;
      for (int j = 0; j < NN; ++j)
        if (adjm[i * 129 + j] != 0.f) {
          const float wgt = __expf(lrelu(f1i + gxls[j] * s2 + t2) - m);
          ssum += wgt; ps += wgt * gxls[j];
        }
      p[i] = ps / ssum;
    }
    __syncthreads();
    if (tid < NN) {
      const int i = tid;
      float xg1[16];
#pragma unroll
      for (int f = 0; f < 16; ++f) {
        const float ov = p[i] * u[f] + v[f];
        xg1[f] = ov > 0.f ? ov : expm1f(ov);
      }
      float wrow[8];
#pragma unroll
      for (int f2 = 0; f2 < 8; ++f2) wrow[f2] = 0.f;
#pragma unroll
      for (int f = 0; f < 16; ++f) {
        const float xv = xg1[f];
#pragma unroll
        for (int f2 = 0; f2 < 8; ++f2) wrow[f2] += xv * W2[f * 8 + f2];
      }
      float fb1 = 0.f, fb2 = 0.f;
#pragma unroll
      for (int f2 = 0; f2 < 8; ++f2) {
        Wh2[i][f2] = wrow[f2];
        fb1 += wrow[f2] * a2[f2];
        fb2 += wrow[f2] * a2[8 + f2];
      }
      f1b[i] = fb1; f2b[i] = fb2;
    }
    __syncthreads();
    if (tid < NN) {
      const int i = tid;
      const float fi = f1b[i];
      float m = -1e30f;
      for (int j = 0; j < NN; ++j)
        if (adjm[i * 129 + j] != 0.f)
          m = fmaxf(m, lrelu(fi + f2b[j]));
      float ssum = 0.f;
      float o[8];
#pragma unroll
      for (int f2 = 0; f2 < 8; ++f2) o[f2] = 0.f;
      for (int j = 0; j < NN; ++j)
        if (adjm[i * 129 + j] != 0.f) {
          const float wgt = __expf(lrelu(fi + f2b[j]) - m);
          ssum += wgt;
#pragma unroll
          for (int f2 = 0; f2 < 8; ++f2) o[f2] += wgt * Wh2[j][f2];
        }
      const float inv = 1.f / ssum;
#pragma unroll
      for (int f2 = 0; f2 < 8; ++f2)
        xg[b * (NN * 8) + i * 8 + f2] = o[f2] * inv;
    }
    __syncthreads();
    if (tid == 0)
      __hip_atomic_store(&flags[256 + b], MAGIC, __ATOMIC_RELEASE,
                         __HIP_MEMORY_SCOPE_AGENT);
    return;
  }

  // =================== CONSUMER: wave-specialized LSTM pipeline ============
  const int b   = bid;
  const int t   = tid;
  const int wid = t >> 6;           // wave role 0..3 (wave3: polls + barriers)
  const int l   = t & 63;           // lane = unit

  // 16-deep packed-f16 h buffers (32 dwords each) + 16-deep SB float4 buffer.
  __shared__ __align__(16) unsigned hb0[16][32];
  __shared__ __align__(16) unsigned hb1[16][32];
  __shared__ __align__(16) float4 SBb[16][64];
  __shared__ float cbuf[1088];
  __shared__ float hidc[96];

  // Full-row f16 weights: 4 gates x 64 dims = 128 dwords (static indexing).
  const float* Wsrc = (wid == 0) ? Whh0 : (wid == 1) ? Wih1 : Whh1;
  half2v w[4][32];
  if (wid < 3) {
#pragma unroll
    for (int j = 0; j < 4; ++j) {
      const float* wr = Wsrc + (l + 64 * j) * HID;
#pragma unroll
      for (int c = 0; c < 16; ++c) {
        const float4 wv = *reinterpret_cast<const float4*>(wr + 4 * c);
        w[j][2 * c]     = half2v{(_Float16)wv.x, (_Float16)wv.y};
        w[j][2 * c + 1] = half2v{(_Float16)wv.z, (_Float16)wv.w};
      }
    }
  }
  // layer-1 bias, folded into wave1's dot accumulators.
  float4 b1v = make_float4(0.f, 0.f, 0.f, 0.f);
  if (wid == 1) {
    b1v.x = bih1[l]       + bhh1[l];
    b1v.y = bih1[l + 64]  + bhh1[l + 64];
    b1v.z = bih1[l + 128] + bhh1[l + 128];
    b1v.w = bih1[l + 192] + bhh1[l + 192];
  }

  // Zero all 16 slots of both h buffers (h0[-1]=h1[-1..]=0): 512 dwords each.
  reinterpret_cast<unsigned*>(hb0)[t] = 0u;
  reinterpret_cast<unsigned*>(hb0)[t + 256] = 0u;
  reinterpret_cast<unsigned*>(hb1)[t] = 0u;
  reinterpret_cast<unsigned*>(hb1)[t + 256] = 0u;
  float cst0 = 0.f, cst1 = 0.f;
  const float* X0b = X0T + b * G4 + l * 4;

  // Initial frontier: flags[0..31], polled by wave3 lanes (off wave0's chain).
  int c_ok;
  {
    if (t >= 192 && t < 224) {
      while (__hip_atomic_fetch_add(&flags[t - 192], 0, __ATOMIC_ACQUIRE,
                                    __HIP_MEMORY_SCOPE_AGENT) != MAGIC) {}
    }
    __syncthreads();   // also makes hb0/hb1 zeroing visible
    c_ok = 31;
  }

  // 8-deep X0 prefetch (wave0 consumes; slots reloaded in place after use).
  float4 xa0 = make_float4(0.f, 0.f, 0.f, 0.f);
  float4 xa1 = xa0, xa2 = xa0, xa3 = xa0, xa4 = xa0, xa5 = xa0, xa6 = xa0,
         xa7 = xa0;
  if (wid == 0) {
    xa0 = *reinterpret_cast<const float4*>(X0b + 0 * (BATCH * G4));
    xa1 = *reinterpret_cast<const float4*>(X0b + 1 * (BATCH * G4));
    xa2 = *reinterpret_cast<const float4*>(X0b + 2 * (BATCH * G4));
    xa3 = *reinterpret_cast<const float4*>(X0b + 3 * (BATCH * G4));
    xa4 = *reinterpret_cast<const float4*>(X0b + 4 * (BATCH * G4));
    xa5 = *reinterpret_cast<const float4*>(X0b + 5 * (BATCH * G4));
    xa6 = *reinterpret_cast<const float4*>(X0b + 6 * (BATCH * G4));
    xa7 = *reinterpret_cast<const float4*>(X0b + 7 * (BATCH * G4));
  }

#define LOAD_H8(SRC, RB)                                                       \
  const uint4* hp_ = reinterpret_cast<const uint4*>(&SRC[RB][0]);              \
  const uint4 v0 = hp_[0], v1 = hp_[1], v2 = hp_[2], v3 = hp_[3];              \
  const uint4 v4 = hp_[4], v5 = hp_[5], v6 = hp_[6], v7 = hp_[7]

#define DOT64(G, ACC0)                                                         \
  dot8h(&w[G][24], v6, v7,                                                     \
  dot8h(&w[G][16], v4, v5,                                                     \
  dot8h(&w[G][8],  v2, v3,                                                     \
  dot8h(&w[G][0],  v0, v1, (ACC0)))))

// Interval K (no barrier inside; one barrier per 8 intervals in the loop):
//  wave0: h0[K]    (intra-wave self-loop, slots (K-1)&15 -> K&15)
//  wave1: SB[K-8]  (reads h0[K-8], >=1 epoch old)
//  wave2: h1[K-16] (reads SB[K-16] (>=1 epoch old) + own h1[K-17])
#define INT_STEP(K, XV)                                                        \
  do {                                                                         \
    if (wid == 0) {                                                            \
      if ((K) < SEQ) {                                                         \
        LOAD_H8(hb0, ((K) - 1) & 15);                                          \
        const float A0 = DOT64(0, (XV).x);                                     \
        const float A1 = DOT64(1, (XV).y);                                     \
        const float A2 = DOT64(2, (XV).z);                                     \
        const float A3 = DOT64(3, (XV).w);                                     \
        const float gi = fsigm(A0);                                            \
        const float gf = fsigm(A1);                                            \
        const float gg = ftanh(A2);                                            \
        const float go = fsigm(A3);                                            \
        cst0 = fmaf(gf, cst0, gi * gg);                                        \
        const float hv = go * ftanh(cst0);                                     \
        reinterpret_cast<_Float16*>(&hb0[(K) & 15][0])[l] = (_Float16)hv;      \
      }                                                                        \
    } else if (wid == 1) {                                                     \
      if ((K) >= 8 && (K) <= SEQ + 7) {                                        \
        const int m_ = (K) - 8;                                                \
        LOAD_H8(hb0, m_ & 15);                                                 \
        const float B0 = DOT64(0, b1v.x);                                      \
        const float B1 = DOT64(1, b1v.y);                                      \
        const float B2 = DOT64(2, b1v.z);                                      \
        const float B3 = DOT64(3, b1v.w);                                      \
        SBb[m_ & 15][l] = make_float4(B0, B1, B2, B3);                         \
      }                                                                        \
    } else if (wid == 2) {                                                     \
      if ((K) >= 16) {                                                         \
        const int m_ = (K) - 16;                                               \
        LOAD_H8(hb1, (m_ - 1) & 15);                                           \
        const float C0 = DOT64(0, 0.f);                                        \
        const float C1 = DOT64(1, 0.f);                                        \
        const float C2 = DOT64(2, 0.f);                                        \
        const float C3 = DOT64(3, 0.f);                                        \
        const float4 sb = SBb[m_ & 15][l];                                     \
        const float gi = fsigm(C0 + sb.x);                                     \
        const float gf = fsigm(C1 + sb.y);                                     \
        const float gg = ftanh(C2 + sb.z);                                     \
        const float go = fsigm(C3 + sb.w);                                     \
        cst1 = fmaf(gf, cst1, gi * gg);                                        \
        const float hv = go * ftanh(cst1);                                     \
        reinterpret_cast<_Float16*>(&hb1[m_ & 15][0])[l] = (_Float16)hv;       \
      }                                                                        \
    }                                                                          \
  } while (0)

// Rolling in-place X0 reload for slot I (consumed at interval K = k+I;
// reloads X0[K+8] with ~7 intervals of lead time).
#define XPF(XAI, K)                                                            \
  do {                                                                         \
    if (wid == 0 && (K) + 8 < SEQ)                                             \
      XAI = *reinterpret_cast<const float4*>(X0b + ((K) + 8) * (BATCH * G4));  \
  } while (0)

  for (int k = 0; k < SEQ + 16; k += 8) {   // intervals K=k..k+7 (528 total)
    // Frontier advance: 32-wide batch on wave3 (lanes 192-223); keeps
    // c_ok >= k+16 > k+15 (this epoch's rolling-prefetch reach).
    if (k + 16 > c_ok && c_ok < 255) {
      const int base = c_ok + 1;
      if (t >= 192 && t < 224 && base + (t - 192) <= 255) {
        while (__hip_atomic_fetch_add(&flags[base + (t - 192)], 0,
                                      __ATOMIC_ACQUIRE,
                                      __HIP_MEMORY_SCOPE_AGENT) != MAGIC) {}
      }
      __syncthreads();
      c_ok = (base + 31 < 255) ? base + 31 : 255;
    }
    if (wid < 3) {
#pragma unroll
      for (int j = 0; j < 4; ++j) {
        half2v* wp = &w[j][0];
        asm volatile("" : "+v"(wp[0]), "+v"(wp[1]), "+v"(wp[2]), "+v"(wp[3]),
                          "+v"(wp[4]), "+v"(wp[5]), "+v"(wp[6]), "+v"(wp[7]));
        asm volatile("" : "+v"(wp[8]), "+v"(wp[9]), "+v"(wp[10]), "+v"(wp[11]),
                          "+v"(wp[12]), "+v"(wp[13]), "+v"(wp[14]), "+v"(wp[15]));
        asm volatile("" : "+v"(wp[16]), "+v"(wp[17]), "+v"(wp[18]), "+v"(wp[19]),
                          "+v"(wp[20]), "+v"(wp[21]), "+v"(wp[22]), "+v"(wp[23]));
        asm volatile("" : "+v"(wp[24]), "+v"(wp[25]), "+v"(wp[26]), "+v"(wp[27]),
                          "+v"(wp[28]), "+v"(wp[29]), "+v"(wp[30]), "+v"(wp[31]));
      }
    }
    INT_STEP(k + 0, xa0);  XPF(xa0, k + 0);
    INT_STEP(k + 1, xa1);  XPF(xa1, k + 1);
    INT_STEP(k + 2, xa2);  XPF(xa2, k + 2);
    INT_STEP(k + 3, xa3);  XPF(xa3, k + 3);
    INT_STEP(k + 4, xa4);  XPF(xa4, k + 4);
    INT_STEP(k + 5, xa5);  XPF(xa5, k + 5);
    INT_STEP(k + 6, xa6);  XPF(xa6, k + 6);
    INT_STEP(k + 7, xa7);  XPF(xa7, k + 7);
    BAR_LDS();                      // one barrier per epoch (8 intervals)
  }
#undef XPF
#undef INT_STEP
#undef DOT64
#undef LOAD_H8
  // h1[511] written at interval 527 -> hb1[511 & 15] = hb1[15].

  // wait for this batch's GAT result
  if (t == 0) {
    while (__hip_atomic_fetch_add(&flags[256 + b], 0, __ATOMIC_ACQUIRE,
                                  __HIP_MEMORY_SCOPE_AGENT) != MAGIC) {}
  }
  __syncthreads();

  // ---------------- fused heads: c = [h1(64) | xg_b(1024)] ----------------
  if (t < 64) {
    const _Float16* hh = reinterpret_cast<const _Float16*>(&hb1[15][0]);
    cbuf[t] = (float)hh[t];
  }
  for (int k = t; k < 1024; k += 256) cbuf[64 + k] = xg[b * 1024 + k];
  __syncthreads();
  if (t < 96) {
    const int head = t >> 5, h = t & 31;
    const float* w1 = (head == 0) ? dw1 : (head == 1) ? rw1 : vw1;
    const float* b1 = (head == 0) ? db1 : (head == 1) ? rb1 : vb1;
    float a0 = 0.f, a1v = 0.f, a2v = 0.f, a3v = 0.f;
    for (int k = 0; k < 1088; k += 4) {
      a0  = fmaf(cbuf[k],     w1[k * 32 + h],       a0);
      a1v = fmaf(cbuf[k + 1], w1[(k + 1) * 32 + h], a1v);
      a2v = fmaf(cbuf[k + 2], w1[(k + 2) * 32 + h], a2v);
      a3v = fmaf(cbuf[k + 3], w1[(k + 3) * 32 + h], a3v);
    }
    hidc[head * 32 + h] = fmaxf(b1[h] + ((a0 + a1v) + (a2v + a3v)), 0.f);
  }
  __syncthreads();
  if (t < 4) {
    const int head2 = (t < 2) ? t : 2;
    const int o = (t < 2) ? 0 : (t - 2);
    const int odim = (t < 2) ? 1 : 2;
    const float* w2  = (head2 == 0) ? dw2 : (head2 == 1) ? rw2 : vw2;
    const float* b2p = (head2 == 0) ? db2 : (head2 == 1) ? rb2 : vb2;
    float acc = b2p[o];
    for (int hh = 0; hh < 32; ++hh)
      acc = fmaf(hidc[head2 * 32 + hh], w2[hh * odim + o], acc);
    const int off = (t == 0) ? b : (t == 1) ? (4 + b) : (8 + 2 * b + o);
    out[off] = acc;   // [dir(4) | ret(4) | vol(4x2)] flat
  }
}

// ---------------------------------------------------------------------------
extern "C" void kernel_launch(void* const* d_in, const int* in_sizes, int n_in,
                              void* d_out, int out_size, void* d_ws, size_t ws_size,
                              hipStream_t stream) {
  const float* x     = (const float*)d_in[0];
  const int*   adj   = (const int*)  d_in[1];
  const float* emb_w = (const float*)d_in[2];
  const float* emb_b = (const float*)d_in[3];
  const float* g1W   = (const float*)d_in[4];
  const float* g1a   = (const float*)d_in[5];
  const float* g2W   = (const float*)d_in[6];
  const float* g2a   = (const float*)d_in[7];
  const float* Wih0  = (const float*)d_in[8];
  const float* Whh0  = (const float*)d_in[9];
  const float* bih0  = (const float*)d_in[10];
  const float* bhh0  = (const float*)d_in[11];
  const float* Wih1  = (const float*)d_in[12];
  const float* Whh1  = (const float*)d_in[13];
  const float* bih1  = (const float*)d_in[14];
  const float* bhh1  = (const float*)d_in[15];
  const float* dw1 = (const float*)d_in[16]; const float* db1 = (const float*)d_in[17];
  const float* dw2 = (const float*)d_in[18]; const float* db2 = (const float*)d_in[19];
  const float* rw1 = (const float*)d_in[20]; const float* rb1 = (const float*)d_in[21];
  const float* rw2 = (const float*)d_in[22]; const float* rb2 = (const float*)d_in[23];
  const float* vw1 = (const float*)d_in[24]; const float* vb1 = (const float*)d_in[25];
  const float* vw2 = (const float*)d_in[26]; const float* vb2 = (const float*)d_in[27];

  float* ws = (float*)d_ws;
  float* X0 = ws;                          // SEQ*BATCH*256 floats = 2 MB (transposed)
  float* xg = ws + SEQ * BATCH * G4;       // 4096 floats
  int*  flg = (int*)(xg + BATCH * NN * 8); // 260 flag ints (0xAA-poison = not ready)
  float* out = (float*)d_out;

  hipLaunchKernelGGL(fused_all, dim3(132), dim3(256), 0, stream,
                     x, adj, emb_w, emb_b, g1W, g1a, g2W, g2a,
                     Wih0, Whh0, bih0, bhh0, Wih1, Whh1, bih1, bhh1,
                     dw1, db1, dw2, db2, rw1, rb1, rw2, rb2,
                     vw1, vb1, vw2, vb2,
                     X0, xg, flg, out);
}

// Round 10
// 382.640 us; speedup vs baseline: 1.1928x; 1.1928x over previous
//
#include <hip/hip_runtime.h>

#define SEQ   512
#define BATCH 4
#define NN    128
#define HID   64
#define G4    256   // 4*HID gates per layer
#define MAGIC 0x13579BDF

typedef _Float16 half2v __attribute__((ext_vector_type(2)));

// Fast activations: v_exp_f32 + v_rcp_f32 (abs err ~1e-6, threshold is 1e-3)
__device__ __forceinline__ float frcp(float x)  { return __builtin_amdgcn_rcpf(x); }
__device__ __forceinline__ float fsigm(float x) { return frcp(1.f + __expf(-x)); }
__device__ __forceinline__ float ftanh(float x) { return 1.f - 2.f * frcp(1.f + __expf(2.f * x)); }
__device__ __forceinline__ float lrelu(float x) { return x > 0.f ? x : 0.2f * x; }
__device__ __forceinline__ float dot4f(float4 w, float4 h) {
  return fmaf(w.x, h.x, fmaf(w.y, h.y, fmaf(w.z, h.z, w.w * h.w)));
}
__device__ __forceinline__ void pin4(float4& v) {
  asm volatile("" : "+v"(v.x), "+v"(v.y), "+v"(v.z), "+v"(v.w));
}
__device__ __forceinline__ half2v u2h(unsigned u) {
  return __builtin_bit_cast(half2v, u);
}
// v_dot2_f32_f16: 2 f16 MACs, f32 accumulate (exact products, f32 sum).
__device__ __forceinline__ float fdot2(half2v a, half2v b, float c) {
#if __has_builtin(__builtin_amdgcn_fdot2)
  return __builtin_amdgcn_fdot2(a, b, c, false);
#else
  float d = c;
  asm("v_dot2_f32_f16 %0, %1, %2, %0" : "+v"(d) : "v"(a), "v"(b));
  return d;
#endif
}
// 16-elem f16 dot: 8 chained v_dot2 (w = 8 half2, h = two uint4 of packed f16).
__device__ __forceinline__ float dot8h(const half2v* w, const uint4& a,
                                       const uint4& b, float acc) {
  acc = fdot2(w[0], u2h(a.x), acc);
  acc = fdot2(w[1], u2h(a.y), acc);
  acc = fdot2(w[2], u2h(a.z), acc);
  acc = fdot2(w[3], u2h(a.w), acc);
  acc = fdot2(w[4], u2h(b.x), acc);
  acc = fdot2(w[5], u2h(b.y), acc);
  acc = fdot2(w[6], u2h(b.z), acc);
  acc = fdot2(w[7], u2h(b.w), acc);
  return acc;
}

// LDS-only barrier: s_waitcnt lgkmcnt(0) + s_barrier, NO vmcnt(0) drain.
#define BAR_LDS() asm volatile("s_waitcnt lgkmcnt(0)\n\ts_barrier" ::: "memory")

// ---------------------------------------------------------------------------
// fused_all: ONE kernel, 132 blocks x 256 threads.
//   blocks 0-3   : LSTM scan + heads, gated on banded X0 flags.
//   blocks 4-131 : X0 producer, band-interleaved; blocks 4-7 then GAT.
// R21: epoch = 8 intervals via CONDITIONAL barrier (`if (k & 4)`), keeping
//   R19's 4-INT_STEP loop body (~14KB, fits L1I — R20's 8-step unroll blew
//   the 32KB I-cache and regressed +26%). 16-deep buffers; lags:
//     wave0 @K: h0[K]    = gates(Whh0*h0[K-1] + X0[K])     (intra-wave loop)
//     wave1 @K: SB[K-8]  = Wih1*h0[K-8] + b1               (>=1 barrier behind)
//     wave2 @K: h1[K-16] = gates(SB[K-16] + Whh1*h1[K-17]) (>=1 barrier behind)
//     wave3: frontier polls + barriers only.
//   66 barriers (was 130). 528 intervals; h1[511] lands in hb1[15].
// ---------------------------------------------------------------------------
__global__ __attribute__((amdgpu_flat_work_group_size(256, 256),
                          amdgpu_waves_per_eu(1, 4)))
void fused_all(
    const float* __restrict__ x, const int* __restrict__ adj,
    const float* __restrict__ emb_w, const float* __restrict__ emb_b,
    const float* __restrict__ W1, const float* __restrict__ a1,
    const float* __restrict__ W2, const float* __restrict__ a2,
    const float* __restrict__ Wih0, const float* __restrict__ Whh0,
    const float* __restrict__ bih0, const float* __restrict__ bhh0,
    const float* __restrict__ Wih1, const float* __restrict__ Whh1,
    const float* __restrict__ bih1, const float* __restrict__ bhh1,
    const float* __restrict__ dw1, const float* __restrict__ db1,
    const float* __restrict__ dw2, const float* __restrict__ db2,
    const float* __restrict__ rw1, const float* __restrict__ rb1,
    const float* __restrict__ rw2, const float* __restrict__ rb2,
    const float* __restrict__ vw1, const float* __restrict__ vb1,
    const float* __restrict__ vw2, const float* __restrict__ vb2,
    float* __restrict__ X0T, float* __restrict__ xg,
    int* __restrict__ flags, float* __restrict__ out)
{
  const int bid = blockIdx.x;
  const int tid = threadIdx.x;

  if (bid >= 4) {
    // =================== PRODUCER: band-interleaved X0 ===================
    const int c = bid - 4;
    __shared__ __align__(16) float xls[NN];
    {
      const int g = tid;                       // one gate per thread
      float4 w4[32];
      {
        const float4* wp = reinterpret_cast<const float4*>(Wih0 + g * NN);
#pragma unroll
        for (int i = 0; i < 32; ++i) w4[i] = wp[i];
#pragma unroll
        for (int i = 0; i < 32; ++i) pin4(w4[i]);
      }
      const float bsum = bih0[g] + bhh0[g];
      for (int phase = 0; phase < 4; ++phase) {
        const int T = c + 128 * phase;
        for (int bb = 0; bb < BATCH; ++bb) {
          if (tid < NN) xls[tid] = x[(bb * SEQ + T) * NN + tid];
          __syncthreads();
          {
            const float4* hp = reinterpret_cast<const float4*>(xls);
            float p0 = 0.f, p1 = 0.f, p2 = 0.f, p3 = 0.f;
#pragma unroll
            for (int k = 0; k < 32; k += 4) {
              p0 += dot4f(w4[k],     hp[k]);
              p1 += dot4f(w4[k + 1], hp[k + 1]);
              p2 += dot4f(w4[k + 2], hp[k + 2]);
              p3 += dot4f(w4[k + 3], hp[k + 3]);
            }
            X0T[(4 * T + bb) * G4 + (g & 63) * 4 + (g >> 6)] =
                ((p0 + p1) + (p2 + p3)) + bsum;
          }
          __syncthreads();   // drains this block's X0 stores before flag release
        }
        if (tid == 0 && phase == 0)
          __hip_atomic_store(&flags[c], MAGIC, __ATOMIC_RELEASE,
                             __HIP_MEMORY_SCOPE_AGENT);
        if (tid == 0 && phase == 3)
          __hip_atomic_store(&flags[128 + c], MAGIC, __ATOMIC_RELEASE,
                             __HIP_MEMORY_SCOPE_AGENT);
      }
    }
    if (bid >= 8) return;

    // =================== GAT (blocks 4-7, batch b) ===================
    const int b = bid - 4;
    __shared__ float adjm[NN * 129];
    __shared__ __align__(16) float gxls[NN];
    __shared__ float u[16], v[16];
    __shared__ float Wh2[NN][9];
    __shared__ float f1b[NN], f2b[NN];
    __shared__ float p[NN];

    for (int idx = tid; idx < NN * NN; idx += 256)
      adjm[(idx >> 7) * 129 + (idx & 127)] = (adj[idx] > 0) ? 1.f : 0.f;
    if (tid < NN) gxls[tid] = x[(b * SEQ + (SEQ - 1)) * NN + tid];
    if (tid < 16) {
      float uu = 0.f, vv = 0.f;
      for (int fp = 0; fp < 16; ++fp) {
        uu += emb_w[fp] * W1[fp * 16 + tid];
        vv += emb_b[fp] * W1[fp * 16 + tid];
      }
      u[tid] = uu; v[tid] = vv;
    }
    __syncthreads();
    float s1 = 0.f, t1 = 0.f, s2 = 0.f, t2 = 0.f;
    for (int f = 0; f < 16; ++f) {
      s1 += u[f] * a1[f];      t1 += v[f] * a1[f];
      s2 += u[f] * a1[16 + f]; t2 += v[f] * a1[16 + f];
    }
    if (tid < NN) {
      const int i = tid;
      const float f1i = gxls[i] * s1 + t1;
      float m = -1e30f;
      for (int j = 0; j < NN; ++j)
        if (adjm[i * 129 + j] != 0.f)
          m = fmaxf(m, lrelu(f1i + gxls[j] * s2 + t2));
      float ssum = 0.f, ps = 0.f;
      for (int j = 0; j < NN; ++j)
        if (adjm[i * 129 + j] != 0.f) {
          const float wgt = __expf(lrelu(f1i + gxls[j] * s2 + t2) - m);
          ssum += wgt; ps += wgt * gxls[j];
        }
      p[i] = ps / ssum;
    }
    __syncthreads();
    if (tid < NN) {
      const int i = tid;
      float xg1[16];
#pragma unroll
      for (int f = 0; f < 16; ++f) {
        const float ov = p[i] * u[f] + v[f];
        xg1[f] = ov > 0.f ? ov : expm1f(ov);
      }
      float wrow[8];
#pragma unroll
      for (int f2 = 0; f2 < 8; ++f2) wrow[f2] = 0.f;
#pragma unroll
      for (int f = 0; f < 16; ++f) {
        const float xv = xg1[f];
#pragma unroll
        for (int f2 = 0; f2 < 8; ++f2) wrow[f2] += xv * W2[f * 8 + f2];
      }
      float fb1 = 0.f, fb2 = 0.f;
#pragma unroll
      for (int f2 = 0; f2 < 8; ++f2) {
        Wh2[i][f2] = wrow[f2];
        fb1 += wrow[f2] * a2[f2];
        fb2 += wrow[f2] * a2[8 + f2];
      }
      f1b[i] = fb1; f2b[i] = fb2;
    }
    __syncthreads();
    if (tid < NN) {
      const int i = tid;
      const float fi = f1b[i];
      float m = -1e30f;
      for (int j = 0; j < NN; ++j)
        if (adjm[i * 129 + j] != 0.f)
          m = fmaxf(m, lrelu(fi + f2b[j]));
      float ssum = 0.f;
      float o[8];
#pragma unroll
      for (int f2 = 0; f2 < 8; ++f2) o[f2] = 0.f;
      for (int j = 0; j < NN; ++j)
        if (adjm[i * 129 + j] != 0.f) {
          const float wgt = __expf(lrelu(fi + f2b[j]) - m);
          ssum += wgt;
#pragma unroll
          for (int f2 = 0; f2 < 8; ++f2) o[f2] += wgt * Wh2[j][f2];
        }
      const float inv = 1.f / ssum;
#pragma unroll
      for (int f2 = 0; f2 < 8; ++f2)
        xg[b * (NN * 8) + i * 8 + f2] = o[f2] * inv;
    }
    __syncthreads();
    if (tid == 0)
      __hip_atomic_store(&flags[256 + b], MAGIC, __ATOMIC_RELEASE,
                         __HIP_MEMORY_SCOPE_AGENT);
    return;
  }

  // =================== CONSUMER: wave-specialized LSTM pipeline ============
  const int b   = bid;
  const int t   = tid;
  const int wid = t >> 6;           // wave role 0..3 (wave3: polls + barriers)
  const int l   = t & 63;           // lane = unit

  // 16-deep packed-f16 h buffers (32 dwords each) + 16-deep SB float4 buffer.
  __shared__ __align__(16) unsigned hb0[16][32];
  __shared__ __align__(16) unsigned hb1[16][32];
  __shared__ __align__(16) float4 SBb[16][64];
  __shared__ float cbuf[1088];
  __shared__ float hidc[96];

  // Full-row f16 weights: 4 gates x 64 dims = 128 dwords (static indexing).
  const float* Wsrc = (wid == 0) ? Whh0 : (wid == 1) ? Wih1 : Whh1;
  half2v w[4][32];
  if (wid < 3) {
#pragma unroll
    for (int j = 0; j < 4; ++j) {
      const float* wr = Wsrc + (l + 64 * j) * HID;
#pragma unroll
      for (int c = 0; c < 16; ++c) {
        const float4 wv = *reinterpret_cast<const float4*>(wr + 4 * c);
        w[j][2 * c]     = half2v{(_Float16)wv.x, (_Float16)wv.y};
        w[j][2 * c + 1] = half2v{(_Float16)wv.z, (_Float16)wv.w};
      }
    }
  }
  // layer-1 bias, folded into wave1's dot accumulators.
  float4 b1v = make_float4(0.f, 0.f, 0.f, 0.f);
  if (wid == 1) {
    b1v.x = bih1[l]       + bhh1[l];
    b1v.y = bih1[l + 64]  + bhh1[l + 64];
    b1v.z = bih1[l + 128] + bhh1[l + 128];
    b1v.w = bih1[l + 192] + bhh1[l + 192];
  }

  // Zero all 16 slots of both h buffers (h0[-1]=h1[-1..]=0): 512 dwords each.
  reinterpret_cast<unsigned*>(hb0)[t] = 0u;
  reinterpret_cast<unsigned*>(hb0)[t + 256] = 0u;
  reinterpret_cast<unsigned*>(hb1)[t] = 0u;
  reinterpret_cast<unsigned*>(hb1)[t + 256] = 0u;
  float cst0 = 0.f, cst1 = 0.f;
  const float* X0b = X0T + b * G4 + l * 4;

  // Initial frontier: flags[0..31], polled by wave3 lanes (off wave0's chain).
  int c_ok;
  {
    if (t >= 192 && t < 224) {
      while (__hip_atomic_fetch_add(&flags[t - 192], 0, __ATOMIC_ACQUIRE,
                                    __HIP_MEMORY_SCOPE_AGENT) != MAGIC) {}
    }
    __syncthreads();   // also makes hb0/hb1 zeroing visible
    c_ok = 31;
  }

  // 4-deep X0 prefetch (wave0 consumes) — R19's proven shadow-reg scheme.
  float4 xa0 = make_float4(0.f, 0.f, 0.f, 0.f), xa1 = xa0, xa2 = xa0, xa3 = xa0;
  if (wid == 0) {
    xa0 = *reinterpret_cast<const float4*>(X0b + 0 * (BATCH * G4));
    xa1 = *reinterpret_cast<const float4*>(X0b + 1 * (BATCH * G4));
    xa2 = *reinterpret_cast<const float4*>(X0b + 2 * (BATCH * G4));
    xa3 = *reinterpret_cast<const float4*>(X0b + 3 * (BATCH * G4));
  }

#define LOAD_H8(SRC, RB)                                                       \
  const uint4* hp_ = reinterpret_cast<const uint4*>(&SRC[RB][0]);              \
  const uint4 v0 = hp_[0], v1 = hp_[1], v2 = hp_[2], v3 = hp_[3];              \
  const uint4 v4 = hp_[4], v5 = hp_[5], v6 = hp_[6], v7 = hp_[7]

#define DOT64(G, ACC0)                                                         \
  dot8h(&w[G][24], v6, v7,                                                     \
  dot8h(&w[G][16], v4, v5,                                                     \
  dot8h(&w[G][8],  v2, v3,                                                     \
  dot8h(&w[G][0],  v0, v1, (ACC0)))))

// Interval K (barrier only every 8 intervals, in the loop):
//  wave0: h0[K]    (intra-wave self-loop, slots (K-1)&15 -> K&15)
//  wave1: SB[K-8]  (reads h0[K-8], >=1 barrier old)
//  wave2: h1[K-16] (reads SB[K-16] (>=1 barrier old) + own h1[K-17])
#define INT_STEP(K, XV)                                                        \
  do {                                                                         \
    if (wid == 0) {                                                            \
      if ((K) < SEQ) {                                                         \
        LOAD_H8(hb0, ((K) - 1) & 15);                                          \
        const float A0 = DOT64(0, (XV).x);                                     \
        const float A1 = DOT64(1, (XV).y);                                     \
        const float A2 = DOT64(2, (XV).z);                                     \
        const float A3 = DOT64(3, (XV).w);                                     \
        const float gi = fsigm(A0);                                            \
        const float gf = fsigm(A1);                                            \
        const float gg = ftanh(A2);                                            \
        const float go = fsigm(A3);                                            \
        cst0 = fmaf(gf, cst0, gi * gg);                                        \
        const float hv = go * ftanh(cst0);                                     \
        reinterpret_cast<_Float16*>(&hb0[(K) & 15][0])[l] = (_Float16)hv;      \
      }                                                                        \
    } else if (wid == 1) {                                                     \
      if ((K) >= 8 && (K) <= SEQ + 7) {                                        \
        const int m_ = (K) - 8;                                                \
        LOAD_H8(hb0, m_ & 15);                                                 \
        const float B0 = DOT64(0, b1v.x);                                      \
        const float B1 = DOT64(1, b1v.y);                                      \
        const float B2 = DOT64(2, b1v.z);                                      \
        const float B3 = DOT64(3, b1v.w);                                      \
        SBb[m_ & 15][l] = make_float4(B0, B1, B2, B3);                         \
      }                                                                        \
    } else if (wid == 2) {                                                     \
      if ((K) >= 16) {                                                         \
        const int m_ = (K) - 16;                                               \
        LOAD_H8(hb1, (m_ - 1) & 15);                                           \
        const float C0 = DOT64(0, 0.f);                                        \
        const float C1 = DOT64(1, 0.f);                                        \
        const float C2 = DOT64(2, 0.f);                                        \
        const float C3 = DOT64(3, 0.f);                                        \
        const float4 sb = SBb[m_ & 15][l];                                     \
        const float gi = fsigm(C0 + sb.x);                                     \
        const float gf = fsigm(C1 + sb.y);                                     \
        const float gg = ftanh(C2 + sb.z);                                     \
        const float go = fsigm(C3 + sb.w);                                     \
        cst1 = fmaf(gf, cst1, gi * gg);                                        \
        const float hv = go * ftanh(cst1);                                     \
        reinterpret_cast<_Float16*>(&hb1[m_ & 15][0])[l] = (_Float16)hv;       \
      }                                                                        \
    }                                                                          \
  } while (0)

  for (int k = 0; k < SEQ + 16; k += 4) {   // intervals K=k..k+3 (528 total)
    // Frontier advance: 32-wide batch on wave3 (lanes 192-223).
    if (k + 12 > c_ok && c_ok < 255) {
      const int base = c_ok + 1;
      if (t >= 192 && t < 224 && base + (t - 192) <= 255) {
        while (__hip_atomic_fetch_add(&flags[base + (t - 192)], 0,
                                      __ATOMIC_ACQUIRE,
                                      __HIP_MEMORY_SCOPE_AGENT) != MAGIC) {}
      }
      __syncthreads();
      c_ok = (base + 31 < 255) ? base + 31 : 255;
    }
    if (wid < 3) {
#pragma unroll
      for (int j = 0; j < 4; ++j) {
        half2v* wp = &w[j][0];
        asm volatile("" : "+v"(wp[0]), "+v"(wp[1]), "+v"(wp[2]), "+v"(wp[3]),
                          "+v"(wp[4]), "+v"(wp[5]), "+v"(wp[6]), "+v"(wp[7]));
        asm volatile("" : "+v"(wp[8]), "+v"(wp[9]), "+v"(wp[10]), "+v"(wp[11]),
                          "+v"(wp[12]), "+v"(wp[13]), "+v"(wp[14]), "+v"(wp[15]));
        asm volatile("" : "+v"(wp[16]), "+v"(wp[17]), "+v"(wp[18]), "+v"(wp[19]),
                          "+v"(wp[20]), "+v"(wp[21]), "+v"(wp[22]), "+v"(wp[23]));
        asm volatile("" : "+v"(wp[24]), "+v"(wp[25]), "+v"(wp[26]), "+v"(wp[27]),
                          "+v"(wp[28]), "+v"(wp[29]), "+v"(wp[30]), "+v"(wp[31]));
      }
    }
    // Issue next 4 X0 loads; in flight across the (possible) barrier.
    float4 xb0 = xa0, xb1 = xa1, xb2 = xa2, xb3 = xa3;
    if (wid == 0 && k + 4 < SEQ) {
      xb0 = *reinterpret_cast<const float4*>(X0b + (k + 4) * (BATCH * G4));
      xb1 = *reinterpret_cast<const float4*>(X0b + (k + 5) * (BATCH * G4));
      xb2 = *reinterpret_cast<const float4*>(X0b + (k + 6) * (BATCH * G4));
      xb3 = *reinterpret_cast<const float4*>(X0b + (k + 7) * (BATCH * G4));
    }
    INT_STEP(k,     xa0);
    INT_STEP(k + 1, xa1);
    INT_STEP(k + 2, xa2);
    INT_STEP(k + 3, xa3);
    if (k & 4) BAR_LDS();           // one barrier per 8 intervals (uniform k)
    xa0 = xb0; xa1 = xb1; xa2 = xb2; xa3 = xb3;
  }
#undef INT_STEP
#undef DOT64
#undef LOAD_H8
  // h1[511] written at interval 527 -> hb1[511 & 15] = hb1[15].

  // wait for this batch's GAT result
  if (t == 0) {
    while (__hip_atomic_fetch_add(&flags[256 + b], 0, __ATOMIC_ACQUIRE,
                                  __HIP_MEMORY_SCOPE_AGENT) != MAGIC) {}
  }
  __syncthreads();

  // ---------------- fused heads: c = [h1(64) | xg_b(1024)] ----------------
  if (t < 64) {
    const _Float16* hh = reinterpret_cast<const _Float16*>(&hb1[15][0]);
    cbuf[t] = (float)hh[t];
  }
  for (int k = t; k < 1024; k += 256) cbuf[64 + k] = xg[b * 1024 + k];
  __syncthreads();
  if (t < 96) {
    const int head = t >> 5, h = t & 31;
    const float* w1 = (head == 0) ? dw1 : (head == 1) ? rw1 : vw1;
    const float* b1 = (head == 0) ? db1 : (head == 1) ? rb1 : vb1;
    float a0 = 0.f, a1v = 0.f, a2v = 0.f, a3v = 0.f;
    for (int k = 0; k < 1088; k += 4) {
      a0  = fmaf(cbuf[k],     w1[k * 32 + h],       a0);
      a1v = fmaf(cbuf[k + 1], w1[(k + 1) * 32 + h], a1v);
      a2v = fmaf(cbuf[k + 2], w1[(k + 2) * 32 + h], a2v);
      a3v = fmaf(cbuf[k + 3], w1[(k + 3) * 32 + h], a3v);
    }
    hidc[head * 32 + h] = fmaxf(b1[h] + ((a0 + a1v) + (a2v + a3v)), 0.f);
  }
  __syncthreads();
  if (t < 4) {
    const int head2 = (t < 2) ? t : 2;
    const int o = (t < 2) ? 0 : (t - 2);
    const int odim = (t < 2) ? 1 : 2;
    const float* w2  = (head2 == 0) ? dw2 : (head2 == 1) ? rw2 : vw2;
    const float* b2p = (head2 == 0) ? db2 : (head2 == 1) ? rb2 : vb2;
    float acc = b2p[o];
    for (int hh = 0; hh < 32; ++hh)
      acc = fmaf(hidc[head2 * 32 + hh], w2[hh * odim + o], acc);
    const int off = (t == 0) ? b : (t == 1) ? (4 + b) : (8 + 2 * b + o);
    out[off] = acc;   // [dir(4) | ret(4) | vol(4x2)] flat
  }
}

// ---------------------------------------------------------------------------
extern "C" void kernel_launch(void* const* d_in, const int* in_sizes, int n_in,
                              void* d_out, int out_size, void* d_ws, size_t ws_size,
                              hipStream_t stream) {
  const float* x     = (const float*)d_in[0];
  const int*   adj   = (const int*)  d_in[1];
  const float* emb_w = (const float*)d_in[2];
  const float* emb_b = (const float*)d_in[3];
  const float* g1W   = (const float*)d_in[4];
  const float* g1a   = (const float*)d_in[5];
  const float* g2W   = (const float*)d_in[6];
  const float* g2a   = (const float*)d_in[7];
  const float* Wih0  = (const float*)d_in[8];
  const float* Whh0  = (const float*)d_in[9];
  const float* bih0  = (const float*)d_in[10];
  const float* bhh0  = (const float*)d_in[11];
  const float* Wih1  = (const float*)d_in[12];
  const float* Whh1  = (const float*)d_in[13];
  const float* bih1  = (const float*)d_in[14];
  const float* bhh1  = (const float*)d_in[15];
  const float* dw1 = (const float*)d_in[16]; const float* db1 = (const float*)d_in[17];
  const float* dw2 = (const float*)d_in[18]; const float* db2 = (const float*)d_in[19];
  const float* rw1 = (const float*)d_in[20]; const float* rb1 = (const float*)d_in[21];
  const float* rw2 = (const float*)d_in[22]; const float* rb2 = (const float*)d_in[23];
  const float* vw1 = (const float*)d_in[24]; const float* vb1 = (const float*)d_in[25];
  const float* vw2 = (const float*)d_in[26]; const float* vb2 = (const float*)d_in[27];

  float* ws = (float*)d_ws;
  float* X0 = ws;                          // SEQ*BATCH*256 floats = 2 MB (transposed)
  float* xg = ws + SEQ * BATCH * G4;       // 4096 floats
  int*  flg = (int*)(xg + BATCH * NN * 8); // 260 flag ints (0xAA-poison = not ready)
  float* out = (float*)d_out;

  hipLaunchKernelGGL(fused_all, dim3(132), dim3(256), 0, stream,
                     x, adj, emb_w, emb_b, g1W, g1a, g2W, g2a,
                     Wih0, Whh0, bih0, bhh0, Wih1, Whh1, bih1, bhh1,
                     dw1, db1, dw2, db2, rw1, rb1, rw2, rb2,
                     vw1, vb1, vw2, vb2,
                     X0, xg, flg, out);
}